// Round 3
// baseline (50.327 us; speedup 1.0000x reference)
//
#include <hip/hip_runtime.h>
#include <hip/hip_bf16.h>

// Problem constants (fixed by setup_inputs)
constexpr int kBS     = 32;
constexpr int kMaxLen = 2048;
constexpr int kNNodes = 1364;          // 4 + 16 + 64 + 256 + 1024
constexpr int kNDim   = 1024;
constexpr int kDepth  = 5;
constexpr int kWidth  = 4;
constexpr int kNFeat  = kNDim / (kDepth * kWidth);   // 51
constexpr int kDW     = kDepth * kWidth;             // 20
constexpr int kUsed   = kDW * kNFeat;                // 1020 (cols >= this are zero-pad)

// fp32 in / fp32 out. Evidence: R1 absmax 22.625 == sqrt(512) == tree_norm at
// tanh(p)~0 -> p was fp32 misread as bf16. R0 absmax exactly 18.0 == bf16
// bits of ref-max read back through the fp32 out path -> out is fp32.

__global__ __launch_bounds__(256) void tree_pos_enc_kernel(
    const float* __restrict__ p,          // [64] fp32
    const float* __restrict__ positions,  // [bs, n_nodes, 20] fp32 one-hot
    float* __restrict__ out,              // [bs, max_len, n_dim] fp32
    int total_chunks)   // chunks of 4 floats (16B)
{
    // Per-block weight table: w[d][f] = tanh(p[f])^d * sqrt((1-tanh^2)*n_dim/2)
    __shared__ float s_w[kDepth * kNFeat];   // 255 floats
    {
        int t = threadIdx.x;
        if (t < kDepth * kNFeat) {
            int d = t / kNFeat;
            int f = t - d * kNFeat;
            float tp   = tanhf(p[f]);
            float norm = sqrtf((1.0f - tp * tp) * (float)kNDim * 0.5f);
            float w = norm;
            #pragma unroll
            for (int i = 0; i < kDepth - 1; ++i)   // w *= tp, d times -> tp^d
                if (i < d) w *= tp;
            s_w[t] = w;
        }
    }
    __syncthreads();

    const int stride = gridDim.x * blockDim.x;
    for (int idx = blockIdx.x * blockDim.x + threadIdx.x;
         idx < total_chunks; idx += stride) {
        const int row = idx >> 8;            // 256 16B-chunks per 1024-elem row
        const int c0  = (idx & 255) << 2;    // starting feature column (mult of 4)
        const int b   = row >> 11;           // row / kMaxLen
        const int seq = row & (kMaxLen - 1);

        float vals[4] = {0.0f, 0.0f, 0.0f, 0.0f};
        // kUsed=1020 is a multiple of 4, so a chunk is entirely in-pad or in-use.
        if (!(seq == 0 || seq > kNNodes || c0 >= kUsed)) {
            const int node = seq - 1;
            const float* posrow =
                positions + ((size_t)b * kNNodes + (size_t)node) * kDW;
            #pragma unroll
            for (int j = 0; j < 4; ++j) {
                const int c = c0 + j;
                const int dw = c / kNFeat;           // compiler -> magic-mul
                const int f  = c - dw * kNFeat;
                const float pv = posrow[dw];         // one-hot gate (L1/L2 hit)
                vals[j] = pv * s_w[(dw >> 2) * kNFeat + f];  // dw/width = level d
            }
        }

        *reinterpret_cast<float4*>(out + (size_t)idx * 4) =
            make_float4(vals[0], vals[1], vals[2], vals[3]);
    }
}

extern "C" void kernel_launch(void* const* d_in, const int* in_sizes, int n_in,
                              void* d_out, int out_size, void* d_ws, size_t ws_size,
                              hipStream_t stream) {
    const float* p         = (const float*)d_in[0];
    const float* positions = (const float*)d_in[1];
    float* out             = (float*)d_out;

    const int total_chunks = out_size / 4;   // 4 fp32 per 16B chunk
    const int threads = 256;
    const int blocks  = 2048;                // 8 blocks/CU, grid-stride 32 chunks/thread

    tree_pos_enc_kernel<<<blocks, threads, 0, stream>>>(p, positions, out,
                                                        total_chunks);
}